// Round 2
// baseline (2726.304 us; speedup 1.0000x reference)
//
#include <hip/hip_runtime.h>
#include <hip/hip_bf16.h>
#include <math.h>

// Problem constants (match reference)
#define N_NODES 50000
#define N_EDGES 800000
#define DIN     64
#define HID     128
#define HEADS   4
#define NGRAPH  64
#define NCLS    8
#define EPSB    1e-5f
#define SLOPE   0.2f

typedef __hip_bfloat16 bf16;

__device__ __forceinline__ float b2f(bf16 v) { return __bfloat162float(v); }

// ---------------- CSR build ----------------
__global__ void k_count(const int* __restrict__ ei, int* __restrict__ deg) {
    int e = blockIdx.x * 256 + threadIdx.x;
    if (e < N_EDGES) atomicAdd(&deg[ei[N_EDGES + e]], 1);
}

__global__ void k_scan(const int* __restrict__ deg, int* __restrict__ row_off) {
    __shared__ int sm[1024];
    int carry = 0;
    if (threadIdx.x == 0) row_off[0] = 0;
    for (int base = 0; base < N_NODES; base += 1024) {
        int i = base + threadIdx.x;
        int v = (i < N_NODES) ? deg[i] : 0;
        sm[threadIdx.x] = v;
        __syncthreads();
        for (int off = 1; off < 1024; off <<= 1) {
            int t = (threadIdx.x >= off) ? sm[threadIdx.x - off] : 0;
            __syncthreads();
            sm[threadIdx.x] += t;
            __syncthreads();
        }
        if (i < N_NODES) row_off[i + 1] = carry + sm[threadIdx.x];
        int tot = sm[1023];
        __syncthreads();
        carry += tot;
    }
}

__global__ void k_fill(const int* __restrict__ ei, const int* __restrict__ row_off,
                       int* __restrict__ cursor, int* __restrict__ col) {
    int e = blockIdx.x * 256 + threadIdx.x;
    if (e < N_EDGES) {
        int s = ei[e], d = ei[N_EDGES + e];
        int pos = atomicAdd(&cursor[d], 1);
        col[row_off[d] + pos] = s;
    }
}

// ---------------- SAGE ----------------
template <int C>
__global__ void k_sage_agg(const float* __restrict__ xin, const int* __restrict__ row_off,
                           const int* __restrict__ col, float* __restrict__ agg) {
    int i = blockIdx.x;
    int c = threadIdx.x;
    int s0 = row_off[i], s1 = row_off[i + 1];
    float acc = 0.f;
    for (int j = s0; j < s1; ++j) {
        int s = col[j];
        acc += xin[(size_t)s * C + c];
    }
    float d = (float)(s1 - s0);
    agg[(size_t)i * C + c] = acc / fmaxf(d, 1.0f);
}

// out = prelu(bn(agg@Wl + x@Wr + bias))
template <int K>
__global__ void k_sage_combine(const float* __restrict__ agg, const float* __restrict__ xin,
                               const float* __restrict__ Wl, const float* __restrict__ Wr,
                               const float* __restrict__ bias,
                               const float* __restrict__ bng, const float* __restrict__ bnb,
                               const float* __restrict__ bnm, const float* __restrict__ bnv,
                               const float* __restrict__ pa,
                               float* __restrict__ out) {
    __shared__ float sA[K], sX[K];
    int i = blockIdx.x, j = threadIdx.x;
    if (j < K) {
        sA[j] = agg[(size_t)i * K + j];
        sX[j] = xin[(size_t)i * K + j];
    }
    __syncthreads();
    float acc = 0.f;
    for (int k = 0; k < K; ++k)
        acc += sA[k] * Wl[k * HID + j] + sX[k] * Wr[k * HID + j];
    acc += bias[j];
    float g = bng[j], bb = bnb[j], m = bnm[j], v = bnv[j];
    acc = (acc - m) * rsqrtf(v + EPSB) * g + bb;
    float a = pa[j];
    out[(size_t)i * HID + j] = acc >= 0.f ? acc : a * acc;
}

// ---------------- GAT ----------------
// xw = h @ W  (128 -> 512), stored bf16 (internal buffer; quantization ~0.4% rel)
__global__ void k_gat_xw(const float* __restrict__ h, const float* __restrict__ W,
                         bf16* __restrict__ xw) {
    __shared__ float sH[HID];
    int i = blockIdx.x, j = threadIdx.x; // 512 threads
    if (j < HID) sH[j] = h[(size_t)i * HID + j];
    __syncthreads();
    float acc = 0.f;
    for (int k = 0; k < HID; ++k)
        acc += sH[k] * W[k * (HEADS * HID) + j];
    xw[(size_t)i * (HEADS * HID) + j] = __float2bfloat16(acc);
}

// es[i,h] = sum_c xw[i,h,c]*a_src[h,c]; ed likewise. One wave per (i,h).
__global__ void k_gat_scores(const bf16* __restrict__ xw, const float* __restrict__ as,
                             const float* __restrict__ ad,
                             float* __restrict__ es, float* __restrict__ ed) {
    int wid = (blockIdx.x * 256 + threadIdx.x) >> 6;
    int lane = threadIdx.x & 63;
    if (wid >= N_NODES * HEADS) return;
    int i = wid / HEADS, h = wid % HEADS;
    const bf16* row = xw + (size_t)i * (HEADS * HID) + h * HID;
    float v0 = b2f(row[lane]), v1 = b2f(row[lane + 64]);
    float s1 = v0 * as[h * HID + lane] + v1 * as[h * HID + lane + 64];
    float s2 = v0 * ad[h * HID + lane] + v1 * ad[h * HID + lane + 64];
    for (int off = 32; off; off >>= 1) {
        s1 += __shfl_down(s1, off, 64);
        s2 += __shfl_down(s2, off, 64);
    }
    if (lane == 0) { es[i * HEADS + h] = s1; ed[i * HEADS + h] = s2; }
}

// Per-node GAT aggregation: 4 waves (one per head), two-pass softmax,
// fused head-mean + bias + BN + PReLU.
__global__ void k_gat_agg(const bf16* __restrict__ xw, const float* __restrict__ es,
                          const float* __restrict__ ed, const int* __restrict__ row_off,
                          const int* __restrict__ col, const float* __restrict__ bias,
                          const float* __restrict__ bng, const float* __restrict__ bnb,
                          const float* __restrict__ bnm, const float* __restrict__ bnv,
                          const float* __restrict__ pa,
                          float* __restrict__ out) {
    __shared__ float sO[HEADS][HID];
    int i = blockIdx.x;
    int w = threadIdx.x >> 6;   // head
    int lane = threadIdx.x & 63;
    int s0 = row_off[i], s1 = row_off[i + 1];
    float edi = ed[i * HEADS + w];

    // pass 1: max over incoming edges + self loop (lane-parallel)
    float m;
    {
        float e = es[i * HEADS + w] + edi;           // self loop
        m = e >= 0.f ? e : SLOPE * e;
    }
    for (int j = s0 + lane; j < s1; j += 64) {
        float e = es[col[j] * HEADS + w] + edi;
        e = e >= 0.f ? e : SLOPE * e;
        m = fmaxf(m, e);
    }
    for (int off = 32; off; off >>= 1) m = fmaxf(m, __shfl_down(m, off, 64));
    m = __shfl(m, 0, 64);

    // pass 2: accumulate unnormalized, divide at the end
    float den = 0.f, a0 = 0.f, a1 = 0.f;
    {
        float e = es[i * HEADS + w] + edi;
        e = e >= 0.f ? e : SLOPE * e;
        float ex = expf(e - m);
        den += ex;
        const bf16* r = xw + (size_t)i * (HEADS * HID) + w * HID + 2 * lane;
        a0 += ex * b2f(r[0]);
        a1 += ex * b2f(r[1]);
    }
    for (int j = s0; j < s1; ++j) {
        int s = col[j];
        float e = es[s * HEADS + w] + edi;
        e = e >= 0.f ? e : SLOPE * e;
        float ex = expf(e - m);
        den += ex;
        const bf16* r = xw + (size_t)s * (HEADS * HID) + w * HID + 2 * lane;
        a0 += ex * b2f(r[0]);
        a1 += ex * b2f(r[1]);
    }
    float inv = 1.0f / den;
    sO[w][2 * lane]     = a0 * inv;
    sO[w][2 * lane + 1] = a1 * inv;
    __syncthreads();
    int j = threadIdx.x;
    if (j < HID) {
        float v = 0.25f * (sO[0][j] + sO[1][j] + sO[2][j] + sO[3][j]) + bias[j];
        float g = bng[j], bb = bnb[j], mm = bnm[j], vv = bnv[j];
        v = (v - mm) * rsqrtf(vv + EPSB) * g + bb;
        float a = pa[j];
        out[(size_t)i * HID + j] = v >= 0.f ? v : a * v;
    }
}

// ---------------- MLP / pool / classifier ----------------
template <bool PRELU>
__global__ void k_mlp(const float* __restrict__ in, const float* __restrict__ W,
                      const float* __restrict__ b, const float* __restrict__ a,
                      float* __restrict__ out) {
    __shared__ float sH[HID];
    int i = blockIdx.x, j = threadIdx.x;
    sH[j] = in[(size_t)i * HID + j];
    __syncthreads();
    float acc = b[j];
    for (int k = 0; k < HID; ++k) acc += sH[k] * W[k * HID + j];
    if (PRELU) {
        float al = a[j];
        acc = acc >= 0.f ? acc : al * acc;
    }
    out[(size_t)i * HID + j] = acc;
}

__global__ void k_pool(const float* __restrict__ h, const int* __restrict__ batch,
                       float* __restrict__ pool, float* __restrict__ cnt) {
    int i = blockIdx.x, c = threadIdx.x;
    int g = batch[i];
    atomicAdd(&pool[g * HID + c], h[(size_t)i * HID + c]);
    if (c == 0) atomicAdd(&cnt[g], 1.0f);
}

__global__ void k_cls(const float* __restrict__ pool, const float* __restrict__ cnt,
                      const float* __restrict__ W, const float* __restrict__ b,
                      float* __restrict__ out) {
    int t = threadIdx.x;            // 512 = 64*8
    int g = t / NCLS, n = t % NCLS;
    float ic = 1.0f / fmaxf(cnt[g], 1.0f);
    float acc = b[n];
    for (int k = 0; k < HID; ++k)
        acc += pool[g * HID + k] * ic * W[k * NCLS + n];
    out[g * NCLS + n] = acc;
}

// ---------------- launch ----------------
extern "C" void kernel_launch(void* const* d_in, const int* in_sizes, int n_in,
                              void* d_out, int out_size, void* d_ws, size_t ws_size,
                              hipStream_t stream) {
    const float* x      = (const float*)d_in[0];
    const int*   ei     = (const int*)d_in[1];
    const int*   batch  = (const int*)d_in[2];
    const float* s0_Wl  = (const float*)d_in[3];
    const float* s0_Wr  = (const float*)d_in[4];
    const float* s0_b   = (const float*)d_in[5];
    const float* s1_Wl  = (const float*)d_in[6];
    const float* s1_Wr  = (const float*)d_in[7];
    const float* s1_b   = (const float*)d_in[8];
    const float* bn_g   = (const float*)d_in[9];
    const float* bn_b   = (const float*)d_in[10];
    const float* bn_m   = (const float*)d_in[11];
    const float* bn_v   = (const float*)d_in[12];
    const float* pre_a  = (const float*)d_in[13];
    const float* g0_W   = (const float*)d_in[14];
    const float* g0_as  = (const float*)d_in[15];
    const float* g0_ad  = (const float*)d_in[16];
    const float* g0_bias= (const float*)d_in[17];
    const float* g1_W   = (const float*)d_in[18];
    const float* g1_as  = (const float*)d_in[19];
    const float* g1_ad  = (const float*)d_in[20];
    const float* g1_bias= (const float*)d_in[21];
    const float* idp_W  = (const float*)d_in[22];
    const float* idp_b  = (const float*)d_in[23];
    const float* idp_a  = (const float*)d_in[24];
    const float* cls_W  = (const float*)d_in[25];
    const float* cls_b  = (const float*)d_in[26];
    float* out = (float*)d_out;

    // workspace carve (256B aligned)
    char* p = (char*)d_ws;
    auto alloc = [&](size_t bytes) -> void* {
        void* r = (void*)p;
        p += (bytes + 255) & ~(size_t)255;
        return r;
    };
    int*   deg     = (int*)alloc((size_t)N_NODES * 4);
    int*   cursor  = (int*)alloc((size_t)N_NODES * 4);
    int*   row_off = (int*)alloc((size_t)(N_NODES + 1) * 4);
    int*   col     = (int*)alloc((size_t)N_EDGES * 4);
    float* es      = (float*)alloc((size_t)N_NODES * HEADS * 4);
    float* edv     = (float*)alloc((size_t)N_NODES * HEADS * 4);
    float* pool    = (float*)alloc((size_t)NGRAPH * HID * 4);
    float* cntg    = (float*)alloc((size_t)NGRAPH * 4);
    float* hA      = (float*)alloc((size_t)N_NODES * HID * 4);
    float* hB      = (float*)alloc((size_t)N_NODES * HID * 4);
    // union region: agg (N*128 f32 = 25.6MB) during SAGE, xw (N*512 bf16 = 51.2MB) during GAT
    void*  ureg    = alloc((size_t)N_NODES * HEADS * HID * 2);
    float* agg     = (float*)ureg;
    bf16*  xw      = (bf16*)ureg;

    hipMemsetAsync(deg, 0, (size_t)N_NODES * 4, stream);
    hipMemsetAsync(cursor, 0, (size_t)N_NODES * 4, stream);
    hipMemsetAsync(pool, 0, (size_t)NGRAPH * HID * 4, stream);
    hipMemsetAsync(cntg, 0, (size_t)NGRAPH * 4, stream);

    // CSR build
    k_count<<<(N_EDGES + 255) / 256, 256, 0, stream>>>(ei, deg);
    k_scan<<<1, 1024, 0, stream>>>(deg, row_off);
    k_fill<<<(N_EDGES + 255) / 256, 256, 0, stream>>>(ei, row_off, cursor, col);

    // SAGE 0 (DIN=64 -> HID)
    k_sage_agg<DIN><<<N_NODES, DIN, 0, stream>>>(x, row_off, col, agg);
    k_sage_combine<DIN><<<N_NODES, HID, 0, stream>>>(
        agg, x, s0_Wl, s0_Wr, s0_b,
        bn_g + 0 * HID, bn_b + 0 * HID, bn_m + 0 * HID, bn_v + 0 * HID, pre_a + 0 * HID, hA);

    // SAGE 1 (HID -> HID)
    k_sage_agg<HID><<<N_NODES, HID, 0, stream>>>(hA, row_off, col, agg);
    k_sage_combine<HID><<<N_NODES, HID, 0, stream>>>(
        agg, hA, s1_Wl, s1_Wr, s1_b,
        bn_g + 1 * HID, bn_b + 1 * HID, bn_m + 1 * HID, bn_v + 1 * HID, pre_a + 1 * HID, hB);

    // GAT 0
    k_gat_xw<<<N_NODES, HEADS * HID, 0, stream>>>(hB, g0_W, xw);
    k_gat_scores<<<(N_NODES * HEADS) / 4, 256, 0, stream>>>(xw, g0_as, g0_ad, es, edv);
    k_gat_agg<<<N_NODES, 256, 0, stream>>>(
        xw, es, edv, row_off, col, g0_bias,
        bn_g + 2 * HID, bn_b + 2 * HID, bn_m + 2 * HID, bn_v + 2 * HID, pre_a + 2 * HID, hA);

    // GAT 1
    k_gat_xw<<<N_NODES, HEADS * HID, 0, stream>>>(hA, g1_W, xw);
    k_gat_scores<<<(N_NODES * HEADS) / 4, 256, 0, stream>>>(xw, g1_as, g1_ad, es, edv);
    k_gat_agg<<<N_NODES, 256, 0, stream>>>(
        xw, es, edv, row_off, col, g1_bias,
        bn_g + 3 * HID, bn_b + 3 * HID, bn_m + 3 * HID, bn_v + 3 * HID, pre_a + 3 * HID, hB);

    // IDP MLP
    k_mlp<true><<<N_NODES, HID, 0, stream>>>(hB, idp_W + 0 * HID * HID, idp_b + 0 * HID, idp_a + 0 * HID, hA);
    k_mlp<true><<<N_NODES, HID, 0, stream>>>(hA, idp_W + 1 * HID * HID, idp_b + 1 * HID, idp_a + 1 * HID, hB);
    k_mlp<false><<<N_NODES, HID, 0, stream>>>(hB, idp_W + 2 * HID * HID, idp_b + 2 * HID, idp_a + 0 * HID, hA);

    // global mean pool + classifier
    k_pool<<<N_NODES, HID, 0, stream>>>(hA, batch, pool, cntg);
    k_cls<<<1, NGRAPH * NCLS, 0, stream>>>(pool, cntg, cls_W, cls_b, out);
}

// Round 3
// 1570.734 us; speedup vs baseline: 1.7357x; 1.7357x over previous
//
#include <hip/hip_runtime.h>
#include <hip/hip_bf16.h>
#include <math.h>

// Problem constants (match reference)
#define N_NODES 50000
#define N_EDGES 800000
#define DIN     64
#define HID     128
#define HEADS   4
#define NGRAPH  64
#define NCLS    8
#define EPSB    1e-5f
#define SLOPE   0.2f

#define MPAD    (N_NODES + 64)   // row padding for 64-row GEMM tiles

typedef __hip_bfloat16 bf16;
typedef __attribute__((ext_vector_type(8))) short short8;
typedef __attribute__((ext_vector_type(4))) float f32x4;

__device__ __forceinline__ float b2f(bf16 v) { return __bfloat162float(v); }
__device__ __forceinline__ bf16  f2b(float v) { return __float2bfloat16(v); }
__device__ __forceinline__ float ldf(const bf16* p)  { return __bfloat162float(*p); }
__device__ __forceinline__ float ldf(const float* p) { return *p; }

// ---------------- CSR build ----------------
__global__ void k_count(const int* __restrict__ ei, int* __restrict__ deg) {
    int e = blockIdx.x * 256 + threadIdx.x;
    if (e < N_EDGES) atomicAdd(&deg[ei[N_EDGES + e]], 1);
}

__global__ void k_scan(const int* __restrict__ deg, int* __restrict__ row_off) {
    __shared__ int sm[1024];
    int carry = 0;
    if (threadIdx.x == 0) row_off[0] = 0;
    for (int base = 0; base < N_NODES; base += 1024) {
        int i = base + threadIdx.x;
        int v = (i < N_NODES) ? deg[i] : 0;
        sm[threadIdx.x] = v;
        __syncthreads();
        for (int off = 1; off < 1024; off <<= 1) {
            int t = (threadIdx.x >= off) ? sm[threadIdx.x - off] : 0;
            __syncthreads();
            sm[threadIdx.x] += t;
            __syncthreads();
        }
        if (i < N_NODES) row_off[i + 1] = carry + sm[threadIdx.x];
        int tot = sm[1023];
        __syncthreads();
        carry += tot;
    }
}

__global__ void k_fill(const int* __restrict__ ei, const int* __restrict__ row_off,
                       int* __restrict__ cursor, int* __restrict__ col) {
    int e = blockIdx.x * 256 + threadIdx.x;
    if (e < N_EDGES) {
        int s = ei[e], d = ei[N_EDGES + e];
        int pos = atomicAdd(&cursor[d], 1);
        col[row_off[d] + pos] = s;
    }
}

// ---------------- weight prep: convert to bf16, transposed (Bt[n][k]) ----------------
// s0t: 128x128 (Wcat=[s0_Wl;s0_Wr]) | s1t: 128x256 | g0t,g1t: 512x128 | idpt: 3x(128x128)
__global__ void k_prep(const float* __restrict__ s0Wl, const float* __restrict__ s0Wr,
                       const float* __restrict__ s1Wl, const float* __restrict__ s1Wr,
                       const float* __restrict__ g0W,  const float* __restrict__ g1W,
                       const float* __restrict__ idpW,
                       bf16* __restrict__ s0t, bf16* __restrict__ s1t,
                       bf16* __restrict__ g0t, bf16* __restrict__ g1t,
                       bf16* __restrict__ idpt) {
    int t = blockIdx.x * 256 + threadIdx.x;
    if (t < 16384) { int n = t >> 7, k = t & 127;
        s0t[t] = f2b(k < 64 ? s0Wl[k * 128 + n] : s0Wr[(k - 64) * 128 + n]); return; }
    t -= 16384;
    if (t < 32768) { int n = t >> 8, k = t & 255;
        s1t[t] = f2b(k < 128 ? s1Wl[k * 128 + n] : s1Wr[(k - 128) * 128 + n]); return; }
    t -= 32768;
    if (t < 65536) { int n = t >> 7, k = t & 127; g0t[t] = f2b(g0W[k * 512 + n]); return; }
    t -= 65536;
    if (t < 65536) { int n = t >> 7, k = t & 127; g1t[t] = f2b(g1W[k * 512 + n]); return; }
    t -= 65536;
    if (t < 49152) { int l = t >> 14, r = t & 16383; int n = r >> 7, k = r & 127;
        idpt[t] = f2b(idpW[l * 16384 + k * 128 + n]); }
}

// ---------------- SAGE mean-aggregate + concat self features ----------------
// acat row = [mean_agg(C) | self(C)], stored bf16, row stride 2C
template <typename T, int C>
__global__ void k_sage_agg(const T* __restrict__ xin, const int* __restrict__ row_off,
                           const int* __restrict__ col, bf16* __restrict__ acat) {
    int i = blockIdx.x;
    int c = threadIdx.x;
    int s0 = row_off[i], s1 = row_off[i + 1];
    float acc = 0.f;
    for (int j = s0; j < s1; ++j)
        acc += ldf(&xin[(size_t)col[j] * C + c]);
    acat[(size_t)i * (2 * C) + c]     = f2b(acc / fmaxf((float)(s1 - s0), 1.0f));
    acat[(size_t)i * (2 * C) + C + c] = f2b(ldf(&xin[(size_t)i * C + c]));
}

// ---------------- MFMA GEMM: C[M x Nc] = A[M x K] @ Bt^T, fused epilogue ----------------
// EPI: 0=none  1=bias+BN+PReLU  2=bias+PReLU  3=bias
// wave: 16 rows x NT*16 cols; block: 4 waves = 64 rows.
template <int K, int NT, int EPI>
__global__ __launch_bounds__(256) void k_gemm(
        const bf16* __restrict__ A, const bf16* __restrict__ Bt, bf16* __restrict__ C,
        int M, int Nc,
        const float* __restrict__ bias, const float* __restrict__ bng,
        const float* __restrict__ bnb,  const float* __restrict__ bnm,
        const float* __restrict__ bnv,  const float* __restrict__ pa) {
    int wave = threadIdx.x >> 6, lane = threadIdx.x & 63;
    int ln = lane & 15, q = lane >> 4;
    int m0 = blockIdx.x * 64 + wave * 16;
    int n0 = blockIdx.y * (NT * 16);
    const bf16* arow = A + (size_t)(m0 + ln) * K + q * 8;

    f32x4 acc[NT];
#pragma unroll
    for (int t = 0; t < NT; ++t) acc[t] = (f32x4){0.f, 0.f, 0.f, 0.f};

#pragma unroll
    for (int k = 0; k < K; k += 32) {
        short8 a = *(const short8*)(const void*)(arow + k);
#pragma unroll
        for (int t = 0; t < NT; ++t) {
            short8 b = *(const short8*)(const void*)(Bt + (size_t)(n0 + t * 16 + ln) * K + k + q * 8);
            acc[t] = __builtin_amdgcn_mfma_f32_16x16x32_bf16(a, b, acc[t], 0, 0, 0);
        }
    }

#pragma unroll
    for (int t = 0; t < NT; ++t) {
        int cidx = n0 + t * 16 + ln;
        float bi = 0.f, g = 1.f, bb = 0.f, mm = 0.f, iv = 1.f, al = 1.f;
        if (EPI >= 1) bi = bias[cidx];
        if (EPI == 1) { g = bng[cidx]; bb = bnb[cidx]; mm = bnm[cidx]; iv = rsqrtf(bnv[cidx] + EPSB); }
        if (EPI == 1 || EPI == 2) al = pa[cidx];
#pragma unroll
        for (int r = 0; r < 4; ++r) {
            int mr = m0 + q * 4 + r;
            if (mr < M) {
                float v = acc[t][r] + bi;
                if (EPI == 1) v = (v - mm) * iv * g + bb;
                if (EPI == 1 || EPI == 2) v = v >= 0.f ? v : al * v;
                C[(size_t)mr * Nc + cidx] = f2b(v);
            }
        }
    }
}

// ---------------- GAT ----------------
// es[i,h] = xw[i,h,:]·a_src[h,:]; ed likewise. One wave per (i,h).
__global__ void k_gat_scores(const bf16* __restrict__ xw, const float* __restrict__ as,
                             const float* __restrict__ ad,
                             float* __restrict__ es, float* __restrict__ ed) {
    int wid = (blockIdx.x * 256 + threadIdx.x) >> 6;
    int lane = threadIdx.x & 63;
    if (wid >= N_NODES * HEADS) return;
    int i = wid / HEADS, h = wid % HEADS;
    const bf16* row = xw + (size_t)i * (HEADS * HID) + h * HID;
    float v0 = b2f(row[lane]), v1 = b2f(row[lane + 64]);
    float s1 = v0 * as[h * HID + lane] + v1 * as[h * HID + lane + 64];
    float s2 = v0 * ad[h * HID + lane] + v1 * ad[h * HID + lane + 64];
    for (int off = 32; off; off >>= 1) {
        s1 += __shfl_down(s1, off, 64);
        s2 += __shfl_down(s2, off, 64);
    }
    if (lane == 0) { es[i * HEADS + h] = s1; ed[i * HEADS + h] = s2; }
}

// Per-node GAT aggregation: 4 waves (one per head), two-pass softmax,
// fused head-mean + bias + BN + PReLU. Writes bf16.
__global__ void k_gat_agg(const bf16* __restrict__ xw, const float* __restrict__ es,
                          const float* __restrict__ ed, const int* __restrict__ row_off,
                          const int* __restrict__ col, const float* __restrict__ bias,
                          const float* __restrict__ bng, const float* __restrict__ bnb,
                          const float* __restrict__ bnm, const float* __restrict__ bnv,
                          const float* __restrict__ pa,
                          bf16* __restrict__ out) {
    __shared__ float sO[HEADS][HID];
    int i = blockIdx.x;
    int w = threadIdx.x >> 6;   // head
    int lane = threadIdx.x & 63;
    int s0 = row_off[i], s1 = row_off[i + 1];
    float edi = ed[i * HEADS + w];

    // pass 1: max over incoming edges + self loop (lane-parallel)
    float m;
    {
        float e = es[i * HEADS + w] + edi;
        m = e >= 0.f ? e : SLOPE * e;
    }
    for (int j = s0 + lane; j < s1; j += 64) {
        float e = es[col[j] * HEADS + w] + edi;
        e = e >= 0.f ? e : SLOPE * e;
        m = fmaxf(m, e);
    }
    for (int off = 32; off; off >>= 1) m = fmaxf(m, __shfl_down(m, off, 64));
    m = __shfl(m, 0, 64);

    // pass 2: accumulate unnormalized, divide at the end
    float den = 0.f, a0 = 0.f, a1 = 0.f;
    {
        float e = es[i * HEADS + w] + edi;
        e = e >= 0.f ? e : SLOPE * e;
        float ex = expf(e - m);
        den += ex;
        const bf16* r = xw + (size_t)i * (HEADS * HID) + w * HID + 2 * lane;
        a0 += ex * b2f(r[0]);
        a1 += ex * b2f(r[1]);
    }
    for (int j = s0; j < s1; ++j) {
        int s = col[j];
        float e = es[s * HEADS + w] + edi;
        e = e >= 0.f ? e : SLOPE * e;
        float ex = expf(e - m);
        den += ex;
        const bf16* r = xw + (size_t)s * (HEADS * HID) + w * HID + 2 * lane;
        a0 += ex * b2f(r[0]);
        a1 += ex * b2f(r[1]);
    }
    float inv = 1.0f / den;
    sO[w][2 * lane]     = a0 * inv;
    sO[w][2 * lane + 1] = a1 * inv;
    __syncthreads();
    int j = threadIdx.x;
    if (j < HID) {
        float v = 0.25f * (sO[0][j] + sO[1][j] + sO[2][j] + sO[3][j]) + bias[j];
        float g = bng[j], bb = bnb[j], mm = bnm[j], vv = bnv[j];
        v = (v - mm) * rsqrtf(vv + EPSB) * g + bb;
        float a = pa[j];
        out[(size_t)i * HID + j] = f2b(v >= 0.f ? v : a * v);
    }
}

// ---------------- pool / classifier ----------------
__global__ void k_pool(const bf16* __restrict__ h, const int* __restrict__ batch,
                       float* __restrict__ pool, float* __restrict__ cnt) {
    int i = blockIdx.x, c = threadIdx.x;
    int g = batch[i];
    atomicAdd(&pool[g * HID + c], b2f(h[(size_t)i * HID + c]));
    if (c == 0) atomicAdd(&cnt[g], 1.0f);
}

__global__ void k_cls(const float* __restrict__ pool, const float* __restrict__ cnt,
                      const float* __restrict__ W, const float* __restrict__ b,
                      float* __restrict__ out) {
    int t = threadIdx.x;            // 512 = 64*8
    int g = t / NCLS, n = t % NCLS;
    float ic = 1.0f / fmaxf(cnt[g], 1.0f);
    float acc = b[n];
    for (int k = 0; k < HID; ++k)
        acc += pool[g * HID + k] * ic * W[k * NCLS + n];
    out[g * NCLS + n] = acc;
}

// ---------------- launch ----------------
extern "C" void kernel_launch(void* const* d_in, const int* in_sizes, int n_in,
                              void* d_out, int out_size, void* d_ws, size_t ws_size,
                              hipStream_t stream) {
    const float* x      = (const float*)d_in[0];
    const int*   ei     = (const int*)d_in[1];
    const int*   batch  = (const int*)d_in[2];
    const float* s0_Wl  = (const float*)d_in[3];
    const float* s0_Wr  = (const float*)d_in[4];
    const float* s0_b   = (const float*)d_in[5];
    const float* s1_Wl  = (const float*)d_in[6];
    const float* s1_Wr  = (const float*)d_in[7];
    const float* s1_b   = (const float*)d_in[8];
    const float* bn_g   = (const float*)d_in[9];
    const float* bn_b   = (const float*)d_in[10];
    const float* bn_m   = (const float*)d_in[11];
    const float* bn_v   = (const float*)d_in[12];
    const float* pre_a  = (const float*)d_in[13];
    const float* g0_W   = (const float*)d_in[14];
    const float* g0_as  = (const float*)d_in[15];
    const float* g0_ad  = (const float*)d_in[16];
    const float* g0_bias= (const float*)d_in[17];
    const float* g1_W   = (const float*)d_in[18];
    const float* g1_as  = (const float*)d_in[19];
    const float* g1_ad  = (const float*)d_in[20];
    const float* g1_bias= (const float*)d_in[21];
    const float* idp_W  = (const float*)d_in[22];
    const float* idp_b  = (const float*)d_in[23];
    const float* idp_a  = (const float*)d_in[24];
    const float* cls_W  = (const float*)d_in[25];
    const float* cls_b  = (const float*)d_in[26];
    float* out = (float*)d_out;

    // workspace carve (256B aligned)
    char* p = (char*)d_ws;
    auto alloc = [&](size_t bytes) -> void* {
        void* r = (void*)p;
        p += (bytes + 255) & ~(size_t)255;
        return r;
    };
    int*   deg     = (int*)alloc((size_t)N_NODES * 4);
    int*   cursor  = (int*)alloc((size_t)N_NODES * 4);
    int*   row_off = (int*)alloc((size_t)(N_NODES + 1) * 4);
    int*   col     = (int*)alloc((size_t)N_EDGES * 4);
    float* es      = (float*)alloc((size_t)N_NODES * HEADS * 4);
    float* edv     = (float*)alloc((size_t)N_NODES * HEADS * 4);
    float* pool    = (float*)alloc((size_t)NGRAPH * HID * 4);
    float* cntg    = (float*)alloc((size_t)NGRAPH * 4);
    bf16*  hA      = (bf16*)alloc((size_t)MPAD * HID * 2);
    bf16*  hB      = (bf16*)alloc((size_t)MPAD * HID * 2);
    // union: acat0 (MPAD*128 bf16), acat1 (MPAD*256 bf16), xw (MPAD*512 bf16)
    bf16*  u       = (bf16*)alloc((size_t)MPAD * (HEADS * HID) * 2);
    bf16*  acat0   = u;
    bf16*  acat1   = u;
    bf16*  xw      = u;
    // bf16 transposed weights
    bf16*  s0t     = (bf16*)alloc((size_t)128 * 128 * 2);
    bf16*  s1t     = (bf16*)alloc((size_t)128 * 256 * 2);
    bf16*  g0t     = (bf16*)alloc((size_t)512 * 128 * 2);
    bf16*  g1t     = (bf16*)alloc((size_t)512 * 128 * 2);
    bf16*  idpt    = (bf16*)alloc((size_t)3 * 128 * 128 * 2);

    hipMemsetAsync(deg, 0, (size_t)N_NODES * 4, stream);
    hipMemsetAsync(cursor, 0, (size_t)N_NODES * 4, stream);
    hipMemsetAsync(pool, 0, (size_t)NGRAPH * HID * 4, stream);
    hipMemsetAsync(cntg, 0, (size_t)NGRAPH * 4, stream);

    // weight prep + CSR build
    k_prep<<<(229376 + 255) / 256, 256, 0, stream>>>(s0_Wl, s0_Wr, s1_Wl, s1_Wr,
                                                     g0_W, g1_W, idp_W,
                                                     s0t, s1t, g0t, g1t, idpt);
    k_count<<<(N_EDGES + 255) / 256, 256, 0, stream>>>(ei, deg);
    k_scan<<<1, 1024, 0, stream>>>(deg, row_off);
    k_fill<<<(N_EDGES + 255) / 256, 256, 0, stream>>>(ei, row_off, cursor, col);

    const int MB = (N_NODES + 63) / 64;   // 782 row-blocks

    // SAGE 0: acat0 = [mean|self] (K=128) -> hA
    k_sage_agg<float, DIN><<<N_NODES, DIN, 0, stream>>>(x, row_off, col, acat0);
    k_gemm<128, 8, 1><<<dim3(MB, 1), 256, 0, stream>>>(
        acat0, s0t, hA, N_NODES, HID,
        s0_b, bn_g + 0 * HID, bn_b + 0 * HID, bn_m + 0 * HID, bn_v + 0 * HID, pre_a + 0 * HID);

    // SAGE 1: acat1 = [mean|self] (K=256) -> hB
    k_sage_agg<bf16, HID><<<N_NODES, HID, 0, stream>>>(hA, row_off, col, acat1);
    k_gemm<256, 8, 1><<<dim3(MB, 1), 256, 0, stream>>>(
        acat1, s1t, hB, N_NODES, HID,
        s1_b, bn_g + 1 * HID, bn_b + 1 * HID, bn_m + 1 * HID, bn_v + 1 * HID, pre_a + 1 * HID);

    // GAT 0
    k_gemm<128, 8, 0><<<dim3(MB, 4), 256, 0, stream>>>(
        hB, g0t, xw, N_NODES, HEADS * HID, nullptr, nullptr, nullptr, nullptr, nullptr, nullptr);
    k_gat_scores<<<(N_NODES * HEADS) / 4, 256, 0, stream>>>(xw, g0_as, g0_ad, es, edv);
    k_gat_agg<<<N_NODES, 256, 0, stream>>>(
        xw, es, edv, row_off, col, g0_bias,
        bn_g + 2 * HID, bn_b + 2 * HID, bn_m + 2 * HID, bn_v + 2 * HID, pre_a + 2 * HID, hA);

    // GAT 1
    k_gemm<128, 8, 0><<<dim3(MB, 4), 256, 0, stream>>>(
        hA, g1t, xw, N_NODES, HEADS * HID, nullptr, nullptr, nullptr, nullptr, nullptr, nullptr);
    k_gat_scores<<<(N_NODES * HEADS) / 4, 256, 0, stream>>>(xw, g1_as, g1_ad, es, edv);
    k_gat_agg<<<N_NODES, 256, 0, stream>>>(
        xw, es, edv, row_off, col, g1_bias,
        bn_g + 3 * HID, bn_b + 3 * HID, bn_m + 3 * HID, bn_v + 3 * HID, pre_a + 3 * HID, hB);

    // IDP MLP
    k_gemm<128, 8, 2><<<dim3(MB, 1), 256, 0, stream>>>(
        hB, idpt + 0 * 16384, hA, N_NODES, HID,
        idp_b + 0 * HID, nullptr, nullptr, nullptr, nullptr, idp_a + 0 * HID);
    k_gemm<128, 8, 2><<<dim3(MB, 1), 256, 0, stream>>>(
        hA, idpt + 1 * 16384, hB, N_NODES, HID,
        idp_b + 1 * HID, nullptr, nullptr, nullptr, nullptr, idp_a + 1 * HID);
    k_gemm<128, 8, 3><<<dim3(MB, 1), 256, 0, stream>>>(
        hB, idpt + 2 * 16384, hA, N_NODES, HID,
        idp_b + 2 * HID, nullptr, nullptr, nullptr, nullptr, nullptr);

    // global mean pool + classifier
    k_pool<<<N_NODES, HID, 0, stream>>>(hA, batch, pool, cntg);
    k_cls<<<1, NGRAPH * NCLS, 0, stream>>>(pool, cntg, cls_W, cls_b, out);
}

// Round 4
// 1160.985 us; speedup vs baseline: 2.3483x; 1.3529x over previous
//
#include <hip/hip_runtime.h>
#include <hip/hip_bf16.h>
#include <math.h>

// Problem constants (match reference)
#define N_NODES 50000
#define N_EDGES 800000
#define DIN     64
#define HID     128
#define HEADS   4
#define NGRAPH  64
#define NCLS    8
#define EPSB    1e-5f
#define SLOPE   0.2f
#define PSEG    16               // pooling segments per graph

#define MPAD    (N_NODES + 64)   // row padding for 64-row GEMM tiles

typedef __hip_bfloat16 bf16;
typedef __attribute__((ext_vector_type(8))) short short8;
typedef __attribute__((ext_vector_type(4))) float f32x4;

__device__ __forceinline__ float b2f(bf16 v) { return __bfloat162float(v); }
__device__ __forceinline__ bf16  f2b(float v) { return __float2bfloat16(v); }
__device__ __forceinline__ float lo_f(unsigned v) {
    unsigned u = v << 16; return __builtin_bit_cast(float, u);
}
__device__ __forceinline__ float hi_f(unsigned v) {
    unsigned u = v & 0xffff0000u; return __builtin_bit_cast(float, u);
}

// ---------------- CSR build ----------------
__global__ void k_count(const int* __restrict__ ei, int* __restrict__ deg) {
    int e = blockIdx.x * 256 + threadIdx.x;
    if (e < N_EDGES) atomicAdd(&deg[ei[N_EDGES + e]], 1);
}

__global__ void k_scan(const int* __restrict__ deg, int* __restrict__ row_off) {
    __shared__ int sm[1024];
    int carry = 0;
    if (threadIdx.x == 0) row_off[0] = 0;
    for (int base = 0; base < N_NODES; base += 1024) {
        int i = base + threadIdx.x;
        int v = (i < N_NODES) ? deg[i] : 0;
        sm[threadIdx.x] = v;
        __syncthreads();
        for (int off = 1; off < 1024; off <<= 1) {
            int t = (threadIdx.x >= off) ? sm[threadIdx.x - off] : 0;
            __syncthreads();
            sm[threadIdx.x] += t;
            __syncthreads();
        }
        if (i < N_NODES) row_off[i + 1] = carry + sm[threadIdx.x];
        int tot = sm[1023];
        __syncthreads();
        carry += tot;
    }
}

__global__ void k_fill(const int* __restrict__ ei, const int* __restrict__ row_off,
                       int* __restrict__ cursor, int* __restrict__ col) {
    int e = blockIdx.x * 256 + threadIdx.x;
    if (e < N_EDGES) {
        int s = ei[e], d = ei[N_EDGES + e];
        int pos = atomicAdd(&cursor[d], 1);
        col[row_off[d] + pos] = s;
    }
}

// per-graph start offsets from sorted batch
__global__ void k_bounds(const int* __restrict__ batch, int* __restrict__ gstart) {
    int i = blockIdx.x * 256 + threadIdx.x;
    if (i >= N_NODES) return;
    int b = batch[i];
    int prev = (i == 0) ? -1 : batch[i - 1];
    for (int g = prev + 1; g <= b; ++g) gstart[g] = i;
    if (i == N_NODES - 1)
        for (int g = b + 1; g <= NGRAPH; ++g) gstart[g] = N_NODES;
}

// ---------------- weight prep: convert to bf16, transposed (Bt[n][k]) ----------------
__global__ void k_prep(const float* __restrict__ s0Wl, const float* __restrict__ s0Wr,
                       const float* __restrict__ s1Wl, const float* __restrict__ s1Wr,
                       const float* __restrict__ g0W,  const float* __restrict__ g1W,
                       const float* __restrict__ idpW,
                       bf16* __restrict__ s0t, bf16* __restrict__ s1t,
                       bf16* __restrict__ g0t, bf16* __restrict__ g1t,
                       bf16* __restrict__ idpt) {
    int t = blockIdx.x * 256 + threadIdx.x;
    if (t < 16384) { int n = t >> 7, k = t & 127;
        s0t[t] = f2b(k < 64 ? s0Wl[k * 128 + n] : s0Wr[(k - 64) * 128 + n]); return; }
    t -= 16384;
    if (t < 32768) { int n = t >> 8, k = t & 255;
        s1t[t] = f2b(k < 128 ? s1Wl[k * 128 + n] : s1Wr[(k - 128) * 128 + n]); return; }
    t -= 32768;
    if (t < 65536) { int n = t >> 7, k = t & 127; g0t[t] = f2b(g0W[k * 512 + n]); return; }
    t -= 65536;
    if (t < 65536) { int n = t >> 7, k = t & 127; g1t[t] = f2b(g1W[k * 512 + n]); return; }
    t -= 65536;
    if (t < 49152) { int l = t >> 14, r = t & 16383; int n = r >> 7, k = r & 127;
        idpt[t] = f2b(idpW[l * 16384 + k * 128 + n]); }
}

// ---------------- SAGE mean-aggregate + concat self features ----------------
// fp32 input (SAGE0, C=64): one thread per channel
__global__ void k_sage_agg_f32(const float* __restrict__ xin, const int* __restrict__ row_off,
                               const int* __restrict__ col, bf16* __restrict__ acat) {
    int i = blockIdx.x;
    int c = threadIdx.x;  // 64
    int s0 = row_off[i], s1 = row_off[i + 1];
    float acc = 0.f;
    for (int j = s0; j < s1; ++j)
        acc += xin[(size_t)col[j] * DIN + c];
    acat[(size_t)i * (2 * DIN) + c]       = f2b(acc / fmaxf((float)(s1 - s0), 1.0f));
    acat[(size_t)i * (2 * DIN) + DIN + c] = f2b(xin[(size_t)i * DIN + c]);
}

// bf16 input (SAGE1, C=128): 64 threads, 2 channels/lane via uint loads
__global__ void k_sage_agg_bf(const bf16* __restrict__ xin, const int* __restrict__ row_off,
                              const int* __restrict__ col, bf16* __restrict__ acat) {
    int i = blockIdx.x;
    int c = threadIdx.x;  // 64 lanes, channels 2c,2c+1
    int s0 = row_off[i], s1 = row_off[i + 1];
    const unsigned* xb = (const unsigned*)xin;
    float a0 = 0.f, a1 = 0.f;
    for (int j = s0; j < s1; ++j) {
        unsigned v = xb[(size_t)col[j] * (HID / 2) + c];
        a0 += lo_f(v); a1 += hi_f(v);
    }
    float inv = 1.0f / fmaxf((float)(s1 - s0), 1.0f);
    acat[(size_t)i * (2 * HID) + 2 * c]     = f2b(a0 * inv);
    acat[(size_t)i * (2 * HID) + 2 * c + 1] = f2b(a1 * inv);
    ((unsigned*)acat)[(size_t)i * HID + (HID / 2) + c] = xb[(size_t)i * (HID / 2) + c];
}

// ---------------- MFMA GEMM: C[M x Nc] = A[M x K] @ Bt^T, fused epilogue ----------------
// EPI: 0=none  1=bias+BN+PReLU  2=bias+PReLU  3=bias
template <int K, int NT, int EPI>
__global__ __launch_bounds__(256) void k_gemm(
        const bf16* __restrict__ A, const bf16* __restrict__ Bt, bf16* __restrict__ C,
        int M, int Nc,
        const float* __restrict__ bias, const float* __restrict__ bng,
        const float* __restrict__ bnb,  const float* __restrict__ bnm,
        const float* __restrict__ bnv,  const float* __restrict__ pa) {
    int wave = threadIdx.x >> 6, lane = threadIdx.x & 63;
    int ln = lane & 15, q = lane >> 4;
    int m0 = blockIdx.x * 64 + wave * 16;
    int n0 = blockIdx.y * (NT * 16);
    const bf16* arow = A + (size_t)(m0 + ln) * K + q * 8;

    f32x4 acc[NT];
#pragma unroll
    for (int t = 0; t < NT; ++t) acc[t] = (f32x4){0.f, 0.f, 0.f, 0.f};

#pragma unroll
    for (int k = 0; k < K; k += 32) {
        short8 a = *(const short8*)(const void*)(arow + k);
#pragma unroll
        for (int t = 0; t < NT; ++t) {
            short8 b = *(const short8*)(const void*)(Bt + (size_t)(n0 + t * 16 + ln) * K + k + q * 8);
            acc[t] = __builtin_amdgcn_mfma_f32_16x16x32_bf16(a, b, acc[t], 0, 0, 0);
        }
    }

#pragma unroll
    for (int t = 0; t < NT; ++t) {
        int cidx = n0 + t * 16 + ln;
        float bi = 0.f, g = 1.f, bb = 0.f, mm = 0.f, iv = 1.f, al = 1.f;
        if (EPI >= 1) bi = bias[cidx];
        if (EPI == 1) { g = bng[cidx]; bb = bnb[cidx]; mm = bnm[cidx]; iv = rsqrtf(bnv[cidx] + EPSB); }
        if (EPI == 1 || EPI == 2) al = pa[cidx];
#pragma unroll
        for (int r = 0; r < 4; ++r) {
            int mr = m0 + q * 4 + r;
            if (mr < M) {
                float v = acc[t][r] + bi;
                if (EPI == 1) v = (v - mm) * iv * g + bb;
                if (EPI == 1 || EPI == 2) v = v >= 0.f ? v : al * v;
                C[(size_t)mr * Nc + cidx] = f2b(v);
            }
        }
    }
}

// ---------------- GAT ----------------
__global__ void k_gat_scores(const bf16* __restrict__ xw, const float* __restrict__ as,
                             const float* __restrict__ ad,
                             float* __restrict__ es, float* __restrict__ ed) {
    int wid = (blockIdx.x * 256 + threadIdx.x) >> 6;
    int lane = threadIdx.x & 63;
    if (wid >= N_NODES * HEADS) return;
    int i = wid / HEADS, h = wid % HEADS;
    const bf16* row = xw + (size_t)i * (HEADS * HID) + h * HID;
    float v0 = b2f(row[lane]), v1 = b2f(row[lane + 64]);
    float s1 = v0 * as[h * HID + lane] + v1 * as[h * HID + lane + 64];
    float s2 = v0 * ad[h * HID + lane] + v1 * ad[h * HID + lane + 64];
    for (int off = 32; off; off >>= 1) {
        s1 += __shfl_down(s1, off, 64);
        s2 += __shfl_down(s2, off, 64);
    }
    if (lane == 0) { es[i * HEADS + h] = s1; ed[i * HEADS + h] = s2; }
}

__global__ void k_gat_agg(const bf16* __restrict__ xw, const float* __restrict__ es,
                          const float* __restrict__ ed, const int* __restrict__ row_off,
                          const int* __restrict__ col, const float* __restrict__ bias,
                          const float* __restrict__ bng, const float* __restrict__ bnb,
                          const float* __restrict__ bnm, const float* __restrict__ bnv,
                          const float* __restrict__ pa,
                          bf16* __restrict__ out) {
    __shared__ float sO[HEADS][HID];
    int i = blockIdx.x;
    int w = threadIdx.x >> 6;   // head
    int lane = threadIdx.x & 63;
    int s0 = row_off[i], s1 = row_off[i + 1];
    float edi = ed[i * HEADS + w];

    float m;
    {
        float e = es[i * HEADS + w] + edi;
        m = e >= 0.f ? e : SLOPE * e;
    }
    for (int j = s0 + lane; j < s1; j += 64) {
        float e = es[col[j] * HEADS + w] + edi;
        e = e >= 0.f ? e : SLOPE * e;
        m = fmaxf(m, e);
    }
    for (int off = 32; off; off >>= 1) m = fmaxf(m, __shfl_down(m, off, 64));
    m = __shfl(m, 0, 64);

    float den = 0.f, a0 = 0.f, a1 = 0.f;
    {
        float e = es[i * HEADS + w] + edi;
        e = e >= 0.f ? e : SLOPE * e;
        float ex = expf(e - m);
        den += ex;
        unsigned v = ((const unsigned*)xw)[(size_t)i * (HEADS * HID / 2) + w * (HID / 2) + lane];
        a0 += ex * lo_f(v);
        a1 += ex * hi_f(v);
    }
    for (int j = s0; j < s1; ++j) {
        int s = col[j];
        float e = es[s * HEADS + w] + edi;
        e = e >= 0.f ? e : SLOPE * e;
        float ex = expf(e - m);
        den += ex;
        unsigned v = ((const unsigned*)xw)[(size_t)s * (HEADS * HID / 2) + w * (HID / 2) + lane];
        a0 += ex * lo_f(v);
        a1 += ex * hi_f(v);
    }
    float inv = 1.0f / den;
    sO[w][2 * lane]     = a0 * inv;
    sO[w][2 * lane + 1] = a1 * inv;
    __syncthreads();
    int j = threadIdx.x;
    if (j < HID) {
        float v = 0.25f * (sO[0][j] + sO[1][j] + sO[2][j] + sO[3][j]) + bias[j];
        float g = bng[j], bb = bnb[j], mm = bnm[j], vv = bnv[j];
        v = (v - mm) * rsqrtf(vv + EPSB) * g + bb;
        float a = pa[j];
        out[(size_t)i * HID + j] = f2b(v >= 0.f ? v : a * v);
    }
}

// ---------------- pool / classifier ----------------
// one block per (graph, segment): register-accumulate contiguous rows, 1 atomic/channel-pair
__global__ void k_pool(const bf16* __restrict__ h, const int* __restrict__ gstart,
                       float* __restrict__ pool) {
    int g = blockIdx.x, s = blockIdx.y;
    int c = threadIdx.x;   // 64 lanes, channels 2c,2c+1
    int b0 = gstart[g], b1 = gstart[g + 1];
    int len = b1 - b0;
    if (len <= 0) return;
    int per = (len + PSEG - 1) / PSEG;
    int r0 = b0 + s * per;
    int r1 = min(r0 + per, b1);
    if (r0 >= r1) return;
    const unsigned* hb = (const unsigned*)h;
    float a0 = 0.f, a1 = 0.f;
    for (int i = r0; i < r1; ++i) {
        unsigned v = hb[(size_t)i * (HID / 2) + c];
        a0 += lo_f(v); a1 += hi_f(v);
    }
    atomicAdd(&pool[g * HID + 2 * c], a0);
    atomicAdd(&pool[g * HID + 2 * c + 1], a1);
}

__global__ void k_cls(const float* __restrict__ pool, const int* __restrict__ gstart,
                      const float* __restrict__ W, const float* __restrict__ b,
                      float* __restrict__ out) {
    int t = threadIdx.x;            // 512 = 64*8
    int g = t / NCLS, n = t % NCLS;
    float ic = 1.0f / fmaxf((float)(gstart[g + 1] - gstart[g]), 1.0f);
    float acc = b[n];
    for (int k = 0; k < HID; ++k)
        acc += pool[g * HID + k] * ic * W[k * NCLS + n];
    out[g * NCLS + n] = acc;
}

// ---------------- launch ----------------
extern "C" void kernel_launch(void* const* d_in, const int* in_sizes, int n_in,
                              void* d_out, int out_size, void* d_ws, size_t ws_size,
                              hipStream_t stream) {
    const float* x      = (const float*)d_in[0];
    const int*   ei     = (const int*)d_in[1];
    const int*   batch  = (const int*)d_in[2];
    const float* s0_Wl  = (const float*)d_in[3];
    const float* s0_Wr  = (const float*)d_in[4];
    const float* s0_b   = (const float*)d_in[5];
    const float* s1_Wl  = (const float*)d_in[6];
    const float* s1_Wr  = (const float*)d_in[7];
    const float* s1_b   = (const float*)d_in[8];
    const float* bn_g   = (const float*)d_in[9];
    const float* bn_b   = (const float*)d_in[10];
    const float* bn_m   = (const float*)d_in[11];
    const float* bn_v   = (const float*)d_in[12];
    const float* pre_a  = (const float*)d_in[13];
    const float* g0_W   = (const float*)d_in[14];
    const float* g0_as  = (const float*)d_in[15];
    const float* g0_ad  = (const float*)d_in[16];
    const float* g0_bias= (const float*)d_in[17];
    const float* g1_W   = (const float*)d_in[18];
    const float* g1_as  = (const float*)d_in[19];
    const float* g1_ad  = (const float*)d_in[20];
    const float* g1_bias= (const float*)d_in[21];
    const float* idp_W  = (const float*)d_in[22];
    const float* idp_b  = (const float*)d_in[23];
    const float* idp_a  = (const float*)d_in[24];
    const float* cls_W  = (const float*)d_in[25];
    const float* cls_b  = (const float*)d_in[26];
    float* out = (float*)d_out;

    // workspace carve (256B aligned)
    char* p = (char*)d_ws;
    auto alloc = [&](size_t bytes) -> void* {
        void* r = (void*)p;
        p += (bytes + 255) & ~(size_t)255;
        return r;
    };
    int*   deg     = (int*)alloc((size_t)N_NODES * 4);
    int*   cursor  = (int*)alloc((size_t)N_NODES * 4);
    int*   row_off = (int*)alloc((size_t)(N_NODES + 1) * 4);
    int*   col     = (int*)alloc((size_t)N_EDGES * 4);
    int*   gstart  = (int*)alloc((size_t)(NGRAPH + 1) * 4);
    float* es      = (float*)alloc((size_t)N_NODES * HEADS * 4);
    float* edv     = (float*)alloc((size_t)N_NODES * HEADS * 4);
    float* pool    = (float*)alloc((size_t)NGRAPH * HID * 4);
    bf16*  hA      = (bf16*)alloc((size_t)MPAD * HID * 2);
    bf16*  hB      = (bf16*)alloc((size_t)MPAD * HID * 2);
    // union: acat0 (MPAD*128 bf16), acat1 (MPAD*256 bf16), xw (MPAD*512 bf16)
    bf16*  u       = (bf16*)alloc((size_t)MPAD * (HEADS * HID) * 2);
    bf16*  acat0   = u;
    bf16*  acat1   = u;
    bf16*  xw      = u;
    // bf16 transposed weights
    bf16*  s0t     = (bf16*)alloc((size_t)128 * 128 * 2);
    bf16*  s1t     = (bf16*)alloc((size_t)128 * 256 * 2);
    bf16*  g0t     = (bf16*)alloc((size_t)512 * 128 * 2);
    bf16*  g1t     = (bf16*)alloc((size_t)512 * 128 * 2);
    bf16*  idpt    = (bf16*)alloc((size_t)3 * 128 * 128 * 2);

    hipMemsetAsync(deg, 0, (size_t)N_NODES * 4, stream);
    hipMemsetAsync(cursor, 0, (size_t)N_NODES * 4, stream);
    hipMemsetAsync(pool, 0, (size_t)NGRAPH * HID * 4, stream);

    // weight prep + CSR build + graph bounds
    k_prep<<<(229376 + 255) / 256, 256, 0, stream>>>(s0_Wl, s0_Wr, s1_Wl, s1_Wr,
                                                     g0_W, g1_W, idp_W,
                                                     s0t, s1t, g0t, g1t, idpt);
    k_count<<<(N_EDGES + 255) / 256, 256, 0, stream>>>(ei, deg);
    k_scan<<<1, 1024, 0, stream>>>(deg, row_off);
    k_fill<<<(N_EDGES + 255) / 256, 256, 0, stream>>>(ei, row_off, cursor, col);
    k_bounds<<<(N_NODES + 255) / 256, 256, 0, stream>>>(batch, gstart);

    const int MB = (N_NODES + 63) / 64;   // 782 row-blocks

    // SAGE 0
    k_sage_agg_f32<<<N_NODES, DIN, 0, stream>>>(x, row_off, col, acat0);
    k_gemm<128, 8, 1><<<dim3(MB, 1), 256, 0, stream>>>(
        acat0, s0t, hA, N_NODES, HID,
        s0_b, bn_g + 0 * HID, bn_b + 0 * HID, bn_m + 0 * HID, bn_v + 0 * HID, pre_a + 0 * HID);

    // SAGE 1
    k_sage_agg_bf<<<N_NODES, 64, 0, stream>>>(hA, row_off, col, acat1);
    k_gemm<256, 8, 1><<<dim3(MB, 1), 256, 0, stream>>>(
        acat1, s1t, hB, N_NODES, HID,
        s1_b, bn_g + 1 * HID, bn_b + 1 * HID, bn_m + 1 * HID, bn_v + 1 * HID, pre_a + 1 * HID);

    // GAT 0
    k_gemm<128, 8, 0><<<dim3(MB, 4), 256, 0, stream>>>(
        hB, g0t, xw, N_NODES, HEADS * HID, nullptr, nullptr, nullptr, nullptr, nullptr, nullptr);
    k_gat_scores<<<(N_NODES * HEADS) / 4, 256, 0, stream>>>(xw, g0_as, g0_ad, es, edv);
    k_gat_agg<<<N_NODES, 256, 0, stream>>>(
        xw, es, edv, row_off, col, g0_bias,
        bn_g + 2 * HID, bn_b + 2 * HID, bn_m + 2 * HID, bn_v + 2 * HID, pre_a + 2 * HID, hA);

    // GAT 1
    k_gemm<128, 8, 0><<<dim3(MB, 4), 256, 0, stream>>>(
        hA, g1t, xw, N_NODES, HEADS * HID, nullptr, nullptr, nullptr, nullptr, nullptr, nullptr);
    k_gat_scores<<<(N_NODES * HEADS) / 4, 256, 0, stream>>>(xw, g1_as, g1_ad, es, edv);
    k_gat_agg<<<N_NODES, 256, 0, stream>>>(
        xw, es, edv, row_off, col, g1_bias,
        bn_g + 3 * HID, bn_b + 3 * HID, bn_m + 3 * HID, bn_v + 3 * HID, pre_a + 3 * HID, hB);

    // IDP MLP
    k_gemm<128, 8, 2><<<dim3(MB, 1), 256, 0, stream>>>(
        hB, idpt + 0 * 16384, hA, N_NODES, HID,
        idp_b + 0 * HID, nullptr, nullptr, nullptr, nullptr, idp_a + 0 * HID);
    k_gemm<128, 8, 2><<<dim3(MB, 1), 256, 0, stream>>>(
        hA, idpt + 1 * 16384, hB, N_NODES, HID,
        idp_b + 1 * HID, nullptr, nullptr, nullptr, nullptr, idp_a + 1 * HID);
    k_gemm<128, 8, 3><<<dim3(MB, 1), 256, 0, stream>>>(
        hB, idpt + 2 * 16384, hA, N_NODES, HID,
        idp_b + 2 * HID, nullptr, nullptr, nullptr, nullptr, nullptr);

    // global mean pool + classifier
    k_pool<<<dim3(NGRAPH, PSEG), 64, 0, stream>>>(hA, gstart, pool);
    k_cls<<<1, NGRAPH * NCLS, 0, stream>>>(pool, gstart, cls_W, cls_b, out);
}

// Round 5
// 985.283 us; speedup vs baseline: 2.7670x; 1.1783x over previous
//
#include <hip/hip_runtime.h>
#include <hip/hip_bf16.h>
#include <math.h>

// Problem constants (match reference)
#define N_NODES 50000
#define N_EDGES 800000
#define DIN     64
#define HID     128
#define HEADS   4
#define NGRAPH  64
#define NCLS    8
#define EPSB    1e-5f
#define SLOPE   0.2f
#define PSEG    16               // pooling segments per graph
#define MAXC    256              // gat_agg edge-chunk per head

#define MPAD    (N_NODES + 64)   // row padding for 64-row GEMM tiles

typedef __hip_bfloat16 bf16;
typedef __attribute__((ext_vector_type(8))) short short8;
typedef __attribute__((ext_vector_type(4))) float f32x4;

__device__ __forceinline__ float b2f(bf16 v) { return __bfloat162float(v); }
__device__ __forceinline__ bf16  f2b(float v) { return __float2bfloat16(v); }
__device__ __forceinline__ float lo_f(unsigned v) {
    unsigned u = v << 16; return __builtin_bit_cast(float, u);
}
__device__ __forceinline__ float hi_f(unsigned v) {
    unsigned u = v & 0xffff0000u; return __builtin_bit_cast(float, u);
}

// ---------------- CSR build ----------------
__global__ void k_count(const int* __restrict__ ei, int* __restrict__ deg) {
    int e = blockIdx.x * 256 + threadIdx.x;
    if (e < N_EDGES) atomicAdd(&deg[ei[N_EDGES + e]], 1);
}

__global__ void k_scan(const int* __restrict__ deg, int* __restrict__ row_off) {
    __shared__ int sm[1024];
    int carry = 0;
    if (threadIdx.x == 0) row_off[0] = 0;
    for (int base = 0; base < N_NODES; base += 1024) {
        int i = base + threadIdx.x;
        int v = (i < N_NODES) ? deg[i] : 0;
        sm[threadIdx.x] = v;
        __syncthreads();
        for (int off = 1; off < 1024; off <<= 1) {
            int t = (threadIdx.x >= off) ? sm[threadIdx.x - off] : 0;
            __syncthreads();
            sm[threadIdx.x] += t;
            __syncthreads();
        }
        if (i < N_NODES) row_off[i + 1] = carry + sm[threadIdx.x];
        int tot = sm[1023];
        __syncthreads();
        carry += tot;
    }
}

__global__ void k_fill(const int* __restrict__ ei, const int* __restrict__ row_off,
                       int* __restrict__ cursor, int* __restrict__ col) {
    int e = blockIdx.x * 256 + threadIdx.x;
    if (e < N_EDGES) {
        int s = ei[e], d = ei[N_EDGES + e];
        int pos = atomicAdd(&cursor[d], 1);
        col[row_off[d] + pos] = s;
    }
}

// per-graph start offsets from sorted batch
__global__ void k_bounds(const int* __restrict__ batch, int* __restrict__ gstart) {
    int i = blockIdx.x * 256 + threadIdx.x;
    if (i >= N_NODES) return;
    int b = batch[i];
    int prev = (i == 0) ? -1 : batch[i - 1];
    for (int g = prev + 1; g <= b; ++g) gstart[g] = i;
    if (i == N_NODES - 1)
        for (int g = b + 1; g <= NGRAPH; ++g) gstart[g] = N_NODES;
}

// ---------------- weight prep: convert to bf16, transposed (Bt[n][k]) ----------------
__global__ void k_prep(const float* __restrict__ s0Wl, const float* __restrict__ s0Wr,
                       const float* __restrict__ s1Wl, const float* __restrict__ s1Wr,
                       const float* __restrict__ g0W,  const float* __restrict__ g1W,
                       const float* __restrict__ idpW,
                       bf16* __restrict__ s0t, bf16* __restrict__ s1t,
                       bf16* __restrict__ g0t, bf16* __restrict__ g1t,
                       bf16* __restrict__ idpt) {
    int t = blockIdx.x * 256 + threadIdx.x;
    if (t < 16384) { int n = t >> 7, k = t & 127;
        s0t[t] = f2b(k < 64 ? s0Wl[k * 128 + n] : s0Wr[(k - 64) * 128 + n]); return; }
    t -= 16384;
    if (t < 32768) { int n = t >> 8, k = t & 255;
        s1t[t] = f2b(k < 128 ? s1Wl[k * 128 + n] : s1Wr[(k - 128) * 128 + n]); return; }
    t -= 32768;
    if (t < 65536) { int n = t >> 7, k = t & 127; g0t[t] = f2b(g0W[k * 512 + n]); return; }
    t -= 65536;
    if (t < 65536) { int n = t >> 7, k = t & 127; g1t[t] = f2b(g1W[k * 512 + n]); return; }
    t -= 65536;
    if (t < 49152) { int l = t >> 14, r = t & 16383; int n = r >> 7, k = r & 127;
        idpt[t] = f2b(idpW[l * 16384 + k * 128 + n]); }
}

// ---------------- SAGE mean-aggregate + concat self features ----------------
__global__ void k_sage_agg_f32(const float* __restrict__ xin, const int* __restrict__ row_off,
                               const int* __restrict__ col, bf16* __restrict__ acat) {
    int i = blockIdx.x;
    int c = threadIdx.x;  // 64
    int s0 = row_off[i], s1 = row_off[i + 1];
    float acc = 0.f;
    for (int j = s0; j < s1; ++j)
        acc += xin[(size_t)col[j] * DIN + c];
    acat[(size_t)i * (2 * DIN) + c]       = f2b(acc / fmaxf((float)(s1 - s0), 1.0f));
    acat[(size_t)i * (2 * DIN) + DIN + c] = f2b(xin[(size_t)i * DIN + c]);
}

__global__ void k_sage_agg_bf(const bf16* __restrict__ xin, const int* __restrict__ row_off,
                              const int* __restrict__ col, bf16* __restrict__ acat) {
    int i = blockIdx.x;
    int c = threadIdx.x;  // 64 lanes, channels 2c,2c+1
    int s0 = row_off[i], s1 = row_off[i + 1];
    const unsigned* xb = (const unsigned*)xin;
    float a0 = 0.f, a1 = 0.f;
    for (int j = s0; j < s1; ++j) {
        unsigned v = xb[(size_t)col[j] * (HID / 2) + c];
        a0 += lo_f(v); a1 += hi_f(v);
    }
    float inv = 1.0f / fmaxf((float)(s1 - s0), 1.0f);
    acat[(size_t)i * (2 * HID) + 2 * c]     = f2b(a0 * inv);
    acat[(size_t)i * (2 * HID) + 2 * c + 1] = f2b(a1 * inv);
    ((unsigned*)acat)[(size_t)i * HID + (HID / 2) + c] = xb[(size_t)i * (HID / 2) + c];
}

// ---------------- MFMA GEMM: C[M x Nc] = A[M x K] @ Bt^T, fused epilogue ----------------
// EPI: 0=none  1=bias+BN+PReLU  2=bias+PReLU  3=bias
template <int K, int NT, int EPI>
__global__ __launch_bounds__(256) void k_gemm(
        const bf16* __restrict__ A, const bf16* __restrict__ Bt, bf16* __restrict__ C,
        int M, int Nc,
        const float* __restrict__ bias, const float* __restrict__ bng,
        const float* __restrict__ bnb,  const float* __restrict__ bnm,
        const float* __restrict__ bnv,  const float* __restrict__ pa) {
    int wave = threadIdx.x >> 6, lane = threadIdx.x & 63;
    int ln = lane & 15, q = lane >> 4;
    int m0 = blockIdx.x * 64 + wave * 16;
    int n0 = blockIdx.y * (NT * 16);
    const bf16* arow = A + (size_t)(m0 + ln) * K + q * 8;

    f32x4 acc[NT];
#pragma unroll
    for (int t = 0; t < NT; ++t) acc[t] = (f32x4){0.f, 0.f, 0.f, 0.f};

#pragma unroll
    for (int k = 0; k < K; k += 32) {
        short8 a = *(const short8*)(const void*)(arow + k);
#pragma unroll
        for (int t = 0; t < NT; ++t) {
            short8 b = *(const short8*)(const void*)(Bt + (size_t)(n0 + t * 16 + ln) * K + k + q * 8);
            acc[t] = __builtin_amdgcn_mfma_f32_16x16x32_bf16(a, b, acc[t], 0, 0, 0);
        }
    }

#pragma unroll
    for (int t = 0; t < NT; ++t) {
        int cidx = n0 + t * 16 + ln;
        float bi = 0.f, g = 1.f, bb = 0.f, mm = 0.f, iv = 1.f, al = 1.f;
        if (EPI >= 1) bi = bias[cidx];
        if (EPI == 1) { g = bng[cidx]; bb = bnb[cidx]; mm = bnm[cidx]; iv = rsqrtf(bnv[cidx] + EPSB); }
        if (EPI == 1 || EPI == 2) al = pa[cidx];
#pragma unroll
        for (int r = 0; r < 4; ++r) {
            int mr = m0 + q * 4 + r;
            if (mr < M) {
                float v = acc[t][r] + bi;
                if (EPI == 1) v = (v - mm) * iv * g + bb;
                if (EPI == 1 || EPI == 2) v = v >= 0.f ? v : al * v;
                C[(size_t)mr * Nc + cidx] = f2b(v);
            }
        }
    }
}

// ---------------- GAT ----------------
__global__ void k_gat_scores(const bf16* __restrict__ xw, const float* __restrict__ as,
                             const float* __restrict__ ad,
                             float* __restrict__ es, float* __restrict__ ed) {
    int wid = (blockIdx.x * 256 + threadIdx.x) >> 6;
    int lane = threadIdx.x & 63;
    if (wid >= N_NODES * HEADS) return;
    int i = wid / HEADS, h = wid % HEADS;
    const bf16* row = xw + (size_t)i * (HEADS * HID) + h * HID;
    float v0 = b2f(row[lane]), v1 = b2f(row[lane + 64]);
    float s1 = v0 * as[h * HID + lane] + v1 * as[h * HID + lane + 64];
    float s2 = v0 * ad[h * HID + lane] + v1 * ad[h * HID + lane + 64];
    for (int off = 32; off; off >>= 1) {
        s1 += __shfl_down(s1, off, 64);
        s2 += __shfl_down(s2, off, 64);
    }
    if (lane == 0) { es[i * HEADS + h] = s1; ed[i * HEADS + h] = s2; }
}

// Per-node GAT aggregation: wave w = head w.
// Phase A: lane-parallel exp-score computation into per-wave LDS (once per edge-head).
// Phase B: serial edge loop, lanes parallel over features; LDS broadcast reads.
__global__ __launch_bounds__(256) void k_gat_agg(
        const bf16* __restrict__ xw, const float* __restrict__ es,
        const float* __restrict__ ed, const int* __restrict__ row_off,
        const int* __restrict__ col, const float* __restrict__ bias,
        const float* __restrict__ bng, const float* __restrict__ bnb,
        const float* __restrict__ bnm, const float* __restrict__ bnv,
        const float* __restrict__ pa,
        bf16* __restrict__ out) {
    __shared__ float sEx[HEADS][MAXC];
    __shared__ int   sCol[HEADS][MAXC];
    __shared__ float sO[HEADS][HID];
    int i = blockIdx.x;
    int w = threadIdx.x >> 6;   // head
    int lane = threadIdx.x & 63;
    int s0 = row_off[i], s1 = row_off[i + 1];
    float edi = ed[i * HEADS + w];
    float esi = es[i * HEADS + w];
    const unsigned* xwb = (const unsigned*)xw;

    // global max over incoming edges + self loop (lane-parallel)
    float m;
    {
        float e = esi + edi;
        m = e >= 0.f ? e : SLOPE * e;
    }
    for (int j = s0 + lane; j < s1; j += 64) {
        float e = es[col[j] * HEADS + w] + edi;
        e = e >= 0.f ? e : SLOPE * e;
        m = fmaxf(m, e);
    }
    for (int off = 32; off; off >>= 1) m = fmaxf(m, __shfl_down(m, off, 64));
    m = __shfl(m, 0, 64);

    float den = 0.f, a0 = 0.f, a1 = 0.f;
    {   // self loop
        float e = esi + edi;
        e = e >= 0.f ? e : SLOPE * e;
        float ex = __expf(e - m);
        den += ex;
        unsigned v = xwb[(size_t)i * (HEADS * HID / 2) + w * (HID / 2) + lane];
        a0 += ex * lo_f(v);
        a1 += ex * hi_f(v);
    }
    for (int c0 = s0; c0 < s1; c0 += MAXC) {
        int cnt = min(MAXC, s1 - c0);
        // phase A: per-edge exp scores (one lane per edge)
        for (int l = lane; l < cnt; l += 64) {
            int s = col[c0 + l];
            float e = es[s * HEADS + w] + edi;
            e = e >= 0.f ? e : SLOPE * e;
            float ex = __expf(e - m);
            den += ex;
            sEx[w][l]  = ex;
            sCol[w][l] = s;
        }
        // same-wave LDS write->read: program-order dependency, no block barrier needed
        // phase B: serial over edges, lanes over features
        for (int e = 0; e < cnt; ++e) {
            float ex = sEx[w][e];
            int s = sCol[w][e];
            unsigned v = xwb[(size_t)s * (HEADS * HID / 2) + w * (HID / 2) + lane];
            a0 += ex * lo_f(v);
            a1 += ex * hi_f(v);
        }
    }
    for (int off = 32; off; off >>= 1) den += __shfl_down(den, off, 64);
    den = __shfl(den, 0, 64);

    float inv = 1.0f / den;
    sO[w][2 * lane]     = a0 * inv;
    sO[w][2 * lane + 1] = a1 * inv;
    __syncthreads();
    int j = threadIdx.x;
    if (j < HID) {
        float v = 0.25f * (sO[0][j] + sO[1][j] + sO[2][j] + sO[3][j]) + bias[j];
        float g = bng[j], bb = bnb[j], mm = bnm[j], vv = bnv[j];
        v = (v - mm) * rsqrtf(vv + EPSB) * g + bb;
        float a = pa[j];
        out[(size_t)i * HID + j] = f2b(v >= 0.f ? v : a * v);
    }
}

// ---------------- pool / classifier ----------------
__global__ void k_pool(const bf16* __restrict__ h, const int* __restrict__ gstart,
                       float* __restrict__ pool) {
    int g = blockIdx.x, s = blockIdx.y;
    int c = threadIdx.x;   // 64 lanes, channels 2c,2c+1
    int b0 = gstart[g], b1 = gstart[g + 1];
    int len = b1 - b0;
    if (len <= 0) return;
    int per = (len + PSEG - 1) / PSEG;
    int r0 = b0 + s * per;
    int r1 = min(r0 + per, b1);
    if (r0 >= r1) return;
    const unsigned* hb = (const unsigned*)h;
    float a0 = 0.f, a1 = 0.f;
    for (int i = r0; i < r1; ++i) {
        unsigned v = hb[(size_t)i * (HID / 2) + c];
        a0 += lo_f(v); a1 += hi_f(v);
    }
    atomicAdd(&pool[g * HID + 2 * c], a0);
    atomicAdd(&pool[g * HID + 2 * c + 1], a1);
}

__global__ void k_cls(const float* __restrict__ pool, const int* __restrict__ gstart,
                      const float* __restrict__ W, const float* __restrict__ b,
                      float* __restrict__ out) {
    int t = threadIdx.x;            // 512 = 64*8
    int g = t / NCLS, n = t % NCLS;
    float ic = 1.0f / fmaxf((float)(gstart[g + 1] - gstart[g]), 1.0f);
    float acc = b[n];
    for (int k = 0; k < HID; ++k)
        acc += pool[g * HID + k] * ic * W[k * NCLS + n];
    out[g * NCLS + n] = acc;
}

// ---------------- launch ----------------
extern "C" void kernel_launch(void* const* d_in, const int* in_sizes, int n_in,
                              void* d_out, int out_size, void* d_ws, size_t ws_size,
                              hipStream_t stream) {
    const float* x      = (const float*)d_in[0];
    const int*   ei     = (const int*)d_in[1];
    const int*   batch  = (const int*)d_in[2];
    const float* s0_Wl  = (const float*)d_in[3];
    const float* s0_Wr  = (const float*)d_in[4];
    const float* s0_b   = (const float*)d_in[5];
    const float* s1_Wl  = (const float*)d_in[6];
    const float* s1_Wr  = (const float*)d_in[7];
    const float* s1_b   = (const float*)d_in[8];
    const float* bn_g   = (const float*)d_in[9];
    const float* bn_b   = (const float*)d_in[10];
    const float* bn_m   = (const float*)d_in[11];
    const float* bn_v   = (const float*)d_in[12];
    const float* pre_a  = (const float*)d_in[13];
    const float* g0_W   = (const float*)d_in[14];
    const float* g0_as  = (const float*)d_in[15];
    const float* g0_ad  = (const float*)d_in[16];
    const float* g0_bias= (const float*)d_in[17];
    const float* g1_W   = (const float*)d_in[18];
    const float* g1_as  = (const float*)d_in[19];
    const float* g1_ad  = (const float*)d_in[20];
    const float* g1_bias= (const float*)d_in[21];
    const float* idp_W  = (const float*)d_in[22];
    const float* idp_b  = (const float*)d_in[23];
    const float* idp_a  = (const float*)d_in[24];
    const float* cls_W  = (const float*)d_in[25];
    const float* cls_b  = (const float*)d_in[26];
    float* out = (float*)d_out;

    // workspace carve (256B aligned)
    char* p = (char*)d_ws;
    auto alloc = [&](size_t bytes) -> void* {
        void* r = (void*)p;
        p += (bytes + 255) & ~(size_t)255;
        return r;
    };
    int*   deg     = (int*)alloc((size_t)N_NODES * 4);
    int*   cursor  = (int*)alloc((size_t)N_NODES * 4);
    int*   row_off = (int*)alloc((size_t)(N_NODES + 1) * 4);
    int*   col     = (int*)alloc((size_t)N_EDGES * 4);
    int*   gstart  = (int*)alloc((size_t)(NGRAPH + 1) * 4);
    float* es      = (float*)alloc((size_t)N_NODES * HEADS * 4);
    float* edv     = (float*)alloc((size_t)N_NODES * HEADS * 4);
    float* pool    = (float*)alloc((size_t)NGRAPH * HID * 4);
    bf16*  hA      = (bf16*)alloc((size_t)MPAD * HID * 2);
    bf16*  hB      = (bf16*)alloc((size_t)MPAD * HID * 2);
    // union: acat0 (MPAD*128 bf16), acat1 (MPAD*256 bf16), xw (MPAD*512 bf16)
    bf16*  u       = (bf16*)alloc((size_t)MPAD * (HEADS * HID) * 2);
    bf16*  acat0   = u;
    bf16*  acat1   = u;
    bf16*  xw      = u;
    // bf16 transposed weights
    bf16*  s0t     = (bf16*)alloc((size_t)128 * 128 * 2);
    bf16*  s1t     = (bf16*)alloc((size_t)128 * 256 * 2);
    bf16*  g0t     = (bf16*)alloc((size_t)512 * 128 * 2);
    bf16*  g1t     = (bf16*)alloc((size_t)512 * 128 * 2);
    bf16*  idpt    = (bf16*)alloc((size_t)3 * 128 * 128 * 2);

    hipMemsetAsync(deg, 0, (size_t)N_NODES * 4, stream);
    hipMemsetAsync(cursor, 0, (size_t)N_NODES * 4, stream);
    hipMemsetAsync(pool, 0, (size_t)NGRAPH * HID * 4, stream);

    // weight prep + CSR build + graph bounds
    k_prep<<<(229376 + 255) / 256, 256, 0, stream>>>(s0_Wl, s0_Wr, s1_Wl, s1_Wr,
                                                     g0_W, g1_W, idp_W,
                                                     s0t, s1t, g0t, g1t, idpt);
    k_count<<<(N_EDGES + 255) / 256, 256, 0, stream>>>(ei, deg);
    k_scan<<<1, 1024, 0, stream>>>(deg, row_off);
    k_fill<<<(N_EDGES + 255) / 256, 256, 0, stream>>>(ei, row_off, cursor, col);
    k_bounds<<<(N_NODES + 255) / 256, 256, 0, stream>>>(batch, gstart);

    const int MB = (N_NODES + 63) / 64;   // 782 row-blocks

    // SAGE 0
    k_sage_agg_f32<<<N_NODES, DIN, 0, stream>>>(x, row_off, col, acat0);
    k_gemm<128, 8, 1><<<dim3(MB, 1), 256, 0, stream>>>(
        acat0, s0t, hA, N_NODES, HID,
        s0_b, bn_g + 0 * HID, bn_b + 0 * HID, bn_m + 0 * HID, bn_v + 0 * HID, pre_a + 0 * HID);

    // SAGE 1
    k_sage_agg_bf<<<N_NODES, 64, 0, stream>>>(hA, row_off, col, acat1);
    k_gemm<256, 8, 1><<<dim3(MB, 1), 256, 0, stream>>>(
        acat1, s1t, hB, N_NODES, HID,
        s1_b, bn_g + 1 * HID, bn_b + 1 * HID, bn_m + 1 * HID, bn_v + 1 * HID, pre_a + 1 * HID);

    // GAT 0
    k_gemm<128, 8, 0><<<dim3(MB, 4), 256, 0, stream>>>(
        hB, g0t, xw, N_NODES, HEADS * HID, nullptr, nullptr, nullptr, nullptr, nullptr, nullptr);
    k_gat_scores<<<(N_NODES * HEADS) / 4, 256, 0, stream>>>(xw, g0_as, g0_ad, es, edv);
    k_gat_agg<<<N_NODES, 256, 0, stream>>>(
        xw, es, edv, row_off, col, g0_bias,
        bn_g + 2 * HID, bn_b + 2 * HID, bn_m + 2 * HID, bn_v + 2 * HID, pre_a + 2 * HID, hA);

    // GAT 1
    k_gemm<128, 8, 0><<<dim3(MB, 4), 256, 0, stream>>>(
        hA, g1t, xw, N_NODES, HEADS * HID, nullptr, nullptr, nullptr, nullptr, nullptr, nullptr);
    k_gat_scores<<<(N_NODES * HEADS) / 4, 256, 0, stream>>>(xw, g1_as, g1_ad, es, edv);
    k_gat_agg<<<N_NODES, 256, 0, stream>>>(
        xw, es, edv, row_off, col, g1_bias,
        bn_g + 3 * HID, bn_b + 3 * HID, bn_m + 3 * HID, bn_v + 3 * HID, pre_a + 3 * HID, hB);

    // IDP MLP
    k_gemm<128, 8, 2><<<dim3(MB, 1), 256, 0, stream>>>(
        hB, idpt + 0 * 16384, hA, N_NODES, HID,
        idp_b + 0 * HID, nullptr, nullptr, nullptr, nullptr, idp_a + 0 * HID);
    k_gemm<128, 8, 2><<<dim3(MB, 1), 256, 0, stream>>>(
        hA, idpt + 1 * 16384, hB, N_NODES, HID,
        idp_b + 1 * HID, nullptr, nullptr, nullptr, nullptr, idp_a + 1 * HID);
    k_gemm<128, 8, 3><<<dim3(MB, 1), 256, 0, stream>>>(
        hB, idpt + 2 * 16384, hA, N_NODES, HID,
        idp_b + 2 * HID, nullptr, nullptr, nullptr, nullptr, nullptr);

    // global mean pool + classifier
    k_pool<<<dim3(NGRAPH, PSEG), 64, 0, stream>>>(hA, gstart, pool);
    k_cls<<<1, NGRAPH * NCLS, 0, stream>>>(pool, gstart, cls_W, cls_b, out);
}